// Round 1
// baseline (9056.857 us; speedup 1.0000x reference)
//
#include <hip/hip_runtime.h>
#include <hip/hip_bf16.h>
#include <hip/hip_cooperative_groups.h>

namespace cg = cooperative_groups;

// Problem sizes
#define BB   512
#define TT   128
#define NA   50
#define HID  1024
#define LDSP 72     // LDS tile row pitch (elements); 64+8 pad -> 2-way bank alias only

typedef __attribute__((ext_vector_type(8))) short v8s;
typedef __attribute__((ext_vector_type(4))) short v4s;
typedef __attribute__((ext_vector_type(4))) float f32x4;
typedef __attribute__((ext_vector_type(2))) unsigned long long u64x2;

// ---- workspace layout (bytes) ----
#define OFF_WIH0 0u          // bf16 [1024][64]  (padded cols 50..63 = 0)   131072
#define OFF_WHH0 131072u     // bf16 [1024][1024]                           2097152
#define OFF_WIH1 2228224u    // bf16 [1024][1024]
#define OFF_WHH1 4325376u    // bf16 [1024][1024]
#define OFF_H1A  6422528u    // bf16 [512][1024] ping
#define OFF_H1B  7471104u    // bf16 [512][1024] pong
#define OFF_H2A  8519680u
#define OFF_H2B  9568256u
#define OFF_H2F  10616832u   // f32 [512][1024] final layer-2 hidden
#define OFF_B0   12713984u   // f32 [1024] b_ih0+b_hh0
#define OFF_B1   12718080u   // f32 [1024] b_ih1+b_hh1
// total 12722176 bytes (~12.1 MB)

__device__ __forceinline__ ushort f2bf(float f) {  // f32 -> bf16 RNE
    union { float f; unsigned u; } v; v.f = f;
    unsigned r = v.u + 0x7fffu + ((v.u >> 16) & 1u);
    return (ushort)(r >> 16);
}

__device__ __forceinline__ float tanh_fast(float x) {
    // exact identity tanh(x) = 1 - 2/(e^{2x}+1); v_exp_f32 based, saturates correctly
    return 1.f - 2.f / (__expf(2.f * x) + 1.f);
}

// MFMA 16x16x32 bf16 fragment: lane l -> row (l&15), k = kk + (l>>4)*4 + j  (j<4)
// and k = kk + 16 + (l>>4)*4 + j for elems 4..7. A and B both loaded with this
// map (B from row-major W, i.e. B^T rows), so any k-permutation error cancels.
__device__ __forceinline__ v8s ld_frag(const ushort* p) {
    v4s lo = *(const v4s*)p;
    v4s hi = *(const v4s*)(p + 16);
    return __builtin_shufflevector(lo, hi, 0, 1, 2, 3, 4, 5, 6, 7);
}

// stage a 64x64 bf16 tile (rows r0.., cols k0..) of row-major src into lds[64][LDSP]
__device__ __forceinline__ void stage_tile(ushort* dst, const ushort* src,
                                           int r0, int k0, int pitch, int tid) {
    int r = tid >> 3;            // 0..31
    int c = (tid & 7) << 3;      // 0,8,...,56 (elements; 16B chunks)
    const ushort* s = src + (size_t)(r0 + r) * pitch + k0 + c;
    *(u64x2*)(dst + r * LDSP + c)        = *(const u64x2*)s;
    *(u64x2*)(dst + (r + 32) * LDSP + c) = *(const u64x2*)(s + (size_t)32 * pitch);
}

__global__ __launch_bounds__(256) void rnn_coop_kernel(
    const float* __restrict__ x,
    const float* __restrict__ wih0, const float* __restrict__ whh0,
    const float* __restrict__ bih0, const float* __restrict__ bhh0,
    const float* __restrict__ wih1, const float* __restrict__ whh1,
    const float* __restrict__ bih1, const float* __restrict__ bhh1,
    char* __restrict__ ws)
{
    cg::grid_group grid = cg::this_grid();
    const int tid  = threadIdx.x;
    const int wg   = blockIdx.x;
    const int gtid = wg * 256 + tid;

    ushort* wb_ih0 = (ushort*)(ws + OFF_WIH0);
    ushort* wb_hh0 = (ushort*)(ws + OFF_WHH0);
    ushort* wb_ih1 = (ushort*)(ws + OFF_WIH1);
    ushort* wb_hh1 = (ushort*)(ws + OFF_WHH1);
    ushort* H1[2]  = { (ushort*)(ws + OFF_H1A), (ushort*)(ws + OFF_H1B) };
    ushort* H2[2]  = { (ushort*)(ws + OFF_H2A), (ushort*)(ws + OFF_H2B) };
    float*  h2f    = (float*)(ws + OFF_H2F);
    float*  bias0  = (float*)(ws + OFF_B0);
    float*  bias1  = (float*)(ws + OFF_B1);

    // ---- prologue: convert weights to bf16, fold biases ----
    for (int i = gtid; i < HID * 64; i += 65536) {
        int h = i >> 6, d = i & 63;
        wb_ih0[i] = f2bf(d < NA ? wih0[h * NA + d] : 0.f);
    }
    for (int i = gtid; i < HID * HID; i += 65536) wb_hh0[i] = f2bf(whh0[i]);
    for (int i = gtid; i < HID * HID; i += 65536) wb_ih1[i] = f2bf(wih1[i]);
    for (int i = gtid; i < HID * HID; i += 65536) wb_hh1[i] = f2bf(whh1[i]);
    for (int i = gtid; i < HID; i += 65536) {
        bias0[i] = bih0[i] + bhh0[i];
        bias1[i] = bih1[i] + bhh1[i];
    }
    grid.sync();

    // ---- tile assignment: WGs 0..127 -> layer1 GEMM (G1), 128..255 -> layer2 (G2)
    const int  isG2 = (wg >= 128);
    const int  w    = isG2 ? wg - 128 : wg;
    const int  m0   = (w >> 4) << 6;          // batch-row tile base (8 tiles)
    const int  n0   = (w & 15) << 6;          // hidden-col tile base (16 tiles)
    const int  wave = tid >> 6, lane = tid & 63;
    const int  wr = wave >> 1, wc = wave & 1; // 2x2 waves over 64x64 tile
    const int  g = lane >> 4, ln = lane & 15;

    __shared__ ushort ldsA[64 * LDSP];
    __shared__ ushort ldsB[64 * LDSP];

    const int rowA = (wr << 5) + ln;
    const int rowB = (wc << 5) + ln;

    // phase it: G1 computes h1_it (it<TT); G2 computes h2_{it-1} (it>=1)
    #pragma unroll 1
    for (int it = 0; it <= TT; ++it) {
        const bool active = isG2 ? (it >= 1) : (it < TT);
        if (active) {
            f32x4 zero = {0.f, 0.f, 0.f, 0.f};
            f32x4 acc[2][2];
            acc[0][0] = zero; acc[0][1] = zero; acc[1][0] = zero; acc[1][1] = zero;

            // G1: chunk 0 = x_t (K=64 padded) vs wb_ih0; chunks 1..16 = h1_prev vs wb_hh0
            // G2: chunks 0..15 = h1_{it-1} vs wb_ih1; 16..31 = h2_{it-2} vs wb_hh1
            const int nchunks = isG2 ? (it == 1 ? 16 : 32) : (it == 0 ? 1 : 17);
            #pragma unroll 1
            for (int c = 0; c < nchunks; ++c) {
                __syncthreads();
                if (!isG2) {
                    if (c == 0) {
                        for (int idx = tid; idx < 64 * 64; idx += 256) {
                            int r = idx >> 6, cc = idx & 63;
                            float v = (cc < NA)
                                ? x[((size_t)(m0 + r) * TT + it) * NA + cc] : 0.f;
                            ldsA[r * LDSP + cc] = f2bf(v);
                        }
                        stage_tile(ldsB, wb_ih0, n0, 0, 64, tid);
                    } else {
                        stage_tile(ldsA, H1[it & 1], m0, (c - 1) << 6, HID, tid);
                        stage_tile(ldsB, wb_hh0,    n0, (c - 1) << 6, HID, tid);
                    }
                } else {
                    if (c < 16) {
                        stage_tile(ldsA, H1[it & 1], m0, c << 6, HID, tid);
                        stage_tile(ldsB, wb_ih1,     n0, c << 6, HID, tid);
                    } else {
                        stage_tile(ldsA, H2[it & 1], m0, (c - 16) << 6, HID, tid);
                        stage_tile(ldsB, wb_hh1,     n0, (c - 16) << 6, HID, tid);
                    }
                }
                __syncthreads();
                #pragma unroll
                for (int kk = 0; kk < 64; kk += 32) {
                    v8s a0 = ld_frag(&ldsA[rowA * LDSP + kk + (g << 2)]);
                    v8s a1 = ld_frag(&ldsA[(rowA + 16) * LDSP + kk + (g << 2)]);
                    v8s b0 = ld_frag(&ldsB[rowB * LDSP + kk + (g << 2)]);
                    v8s b1 = ld_frag(&ldsB[(rowB + 16) * LDSP + kk + (g << 2)]);
                    acc[0][0] = __builtin_amdgcn_mfma_f32_16x16x32_bf16(a0, b0, acc[0][0], 0, 0, 0);
                    acc[0][1] = __builtin_amdgcn_mfma_f32_16x16x32_bf16(a0, b1, acc[0][1], 0, 0, 0);
                    acc[1][0] = __builtin_amdgcn_mfma_f32_16x16x32_bf16(a1, b0, acc[1][0], 0, 0, 0);
                    acc[1][1] = __builtin_amdgcn_mfma_f32_16x16x32_bf16(a1, b1, acc[1][1], 0, 0, 0);
                }
            }

            // epilogue: +bias, tanh, store bf16 (and f32 at final layer-2 step)
            const float* bias = isG2 ? bias1 : bias0;
            ushort* dst = isG2 ? H2[(it + 1) & 1] : H1[(it + 1) & 1];
            #pragma unroll
            for (int fi = 0; fi < 2; ++fi)
            #pragma unroll
            for (int fj = 0; fj < 2; ++fj) {
                int col = n0 + (wc << 5) + (fj << 4) + ln;
                float bv = bias[col];
                #pragma unroll
                for (int j = 0; j < 4; ++j) {
                    int row = m0 + (wr << 5) + (fi << 4) + (g << 2) + j;
                    float v = tanh_fast(acc[fi][fj][j] + bv);
                    dst[(size_t)row * HID + col] = f2bf(v);
                    if (isG2 && it == TT) h2f[(size_t)row * HID + col] = v;
                }
            }
        }
        grid.sync();
    }
}

__device__ __forceinline__ float wsum(float v) {
    #pragma unroll
    for (int off = 32; off > 0; off >>= 1) v += __shfl_xor(v, off);
    return v;
}

__global__ __launch_bounds__(256) void fc_rebalance_kernel(
    const char* __restrict__ ws, const float* __restrict__ fc_w,
    const float* __restrict__ fc_b, float* __restrict__ out)
{
    const float* h2f = (const float*)(ws + OFF_H2F);
    const int wave = threadIdx.x >> 6, lane = threadIdx.x & 63;
    const int b = (blockIdx.x << 2) + wave;   // one wave per sample
    const float* hrow = h2f + (size_t)b * HID;

    float acc = 0.f;
    if (lane < NA) {
        const float* wrow = fc_w + (size_t)lane * HID;
        for (int k = 0; k < HID; k += 4) {
            float4 hv = *(const float4*)(hrow + k);
            float4 wv = *(const float4*)(wrow + k);
            acc += hv.x * wv.x + hv.y * wv.y + hv.z * wv.z + hv.w * wv.w;
        }
        acc += fc_b[lane];
    }

    // softmax over lanes 0..49
    float m = (lane < NA) ? acc : -3.402823466e+38f;
    #pragma unroll
    for (int off = 32; off > 0; off >>= 1) m = fmaxf(m, __shfl_xor(m, off));
    float e = (lane < NA) ? __expf(acc - m) : 0.f;
    float s = wsum(e);
    float p = e / s;

    // iterative box-simplex rebalance, 16 fixed iterations (mirrors reference ops)
    float oldv = p;
    float wcv  = fminf(fmaxf(p, 0.f), 0.3f);
    #pragma unroll 1
    for (int i = 0; i < 16; ++i) {
        float leftover = wsum(oldv - wcv);
        float nom = (wcv != 0.3f) ? wcv : 0.f;
        float S = wsum(nom);
        float wc2 = wcv + leftover * nom / S;
        int cont = __any(wc2 > 0.3f);
        oldv = wc2;
        wcv = cont ? fminf(fmaxf(wc2, 0.f), 0.3f) : wc2;
    }
    if (lane < NA) out[(size_t)b * NA + lane] = wcv;
}

extern "C" void kernel_launch(void* const* d_in, const int* in_sizes, int n_in,
                              void* d_out, int out_size, void* d_ws, size_t ws_size,
                              hipStream_t stream) {
    const float* x    = (const float*)d_in[0];
    const float* wih0 = (const float*)d_in[1];
    const float* whh0 = (const float*)d_in[2];
    const float* bih0 = (const float*)d_in[3];
    const float* bhh0 = (const float*)d_in[4];
    const float* wih1 = (const float*)d_in[5];
    const float* whh1 = (const float*)d_in[6];
    const float* bih1 = (const float*)d_in[7];
    const float* bhh1 = (const float*)d_in[8];
    const float* fcw  = (const float*)d_in[9];
    const float* fcb  = (const float*)d_in[10];
    char* ws   = (char*)d_ws;
    float* out = (float*)d_out;

    void* args[] = { (void*)&x, (void*)&wih0, (void*)&whh0, (void*)&bih0, (void*)&bhh0,
                     (void*)&wih1, (void*)&whh1, (void*)&bih1, (void*)&bhh1, (void*)&ws };
    hipLaunchCooperativeKernel((const void*)rnn_coop_kernel,
                               dim3(256), dim3(256), args, 0, stream);
    fc_rebalance_kernel<<<dim3(128), dim3(256), 0, stream>>>(ws, fcw, fcb, out);
}

// Round 5
// 6664.507 us; speedup vs baseline: 1.3590x; 1.3590x over previous
//
#include <hip/hip_runtime.h>
#include <hip/hip_bf16.h>
#include <hip/hip_cooperative_groups.h>

namespace cg = cooperative_groups;

#define TT   128
#define NA   50
#define HID  1024
#define LDSP 72     // LDS tile row pitch (elements); 64+8 pad -> 2-way bank alias only

typedef __attribute__((ext_vector_type(8))) short v8s;
typedef __attribute__((ext_vector_type(4))) short v4s;
typedef __attribute__((ext_vector_type(4))) float f32x4;
typedef __attribute__((ext_vector_type(2))) unsigned long long u64x2;

// ---- workspace layout (bytes) ---- (round-1 proven layout)
#define OFF_WIH0 0u          // bf16 [1024][64]  (padded cols 50..63 = 0)   131072
#define OFF_WHH0 131072u     // bf16 [1024][1024]                           2097152
#define OFF_WIH1 2228224u    // bf16 [1024][1024]
#define OFF_WHH1 4325376u    // bf16 [1024][1024]
#define OFF_H1A  6422528u    // bf16 [512][1024] ping
#define OFF_H1B  7471104u    // bf16 [512][1024] pong
#define OFF_H2A  8519680u
#define OFF_H2B  9568256u
#define OFF_H2F  10616832u   // f32 [512][1024] final layer-2 hidden
#define OFF_B0   12713984u   // f32 [1024] b_ih0+b_hh0
#define OFF_B1   12718080u   // f32 [1024] b_ih1+b_hh1

__device__ __forceinline__ ushort f2bf(float f) {  // f32 -> bf16 RNE
    union { float f; unsigned u; } v; v.f = f;
    unsigned r = v.u + 0x7fffu + ((v.u >> 16) & 1u);
    return (ushort)(r >> 16);
}

__device__ __forceinline__ float tanh_fast(float x) {
    return 1.f - 2.f / (__expf(2.f * x) + 1.f);   // exact identity, saturates correctly
}

// MFMA 16x16x32 bf16 fragment loader (round-1 proven): elems 0..3 from p[0..3],
// elems 4..7 from p[16..19]; same map for A and B so any k-permutation cancels.
__device__ __forceinline__ v8s ld_frag(const ushort* p) {
    v4s lo = *(const v4s*)p;
    v4s hi = *(const v4s*)(p + 16);
    return __builtin_shufflevector(lo, hi, 0, 1, 2, 3, 4, 5, 6, 7);
}

__global__ __launch_bounds__(256, 1) void rnn_coop_kernel(
    const float* __restrict__ x,
    const float* __restrict__ wih0, const float* __restrict__ whh0,
    const float* __restrict__ bih0, const float* __restrict__ bhh0,
    const float* __restrict__ wih1, const float* __restrict__ whh1,
    const float* __restrict__ bih1, const float* __restrict__ bhh1,
    char* __restrict__ ws)
{
    cg::grid_group grid = cg::this_grid();
    const int tid  = threadIdx.x;
    const int gtid = blockIdx.x * 256 + tid;

    ushort* wb_ih0 = (ushort*)(ws + OFF_WIH0);
    ushort* wb_hh0 = (ushort*)(ws + OFF_WHH0);
    ushort* wb_ih1 = (ushort*)(ws + OFF_WIH1);
    ushort* wb_hh1 = (ushort*)(ws + OFF_WHH1);
    ushort* H1[2]  = { (ushort*)(ws + OFF_H1A), (ushort*)(ws + OFF_H1B) };
    ushort* H2[2]  = { (ushort*)(ws + OFF_H2A), (ushort*)(ws + OFF_H2B) };
    float*  h2f    = (float*)(ws + OFF_H2F);
    float*  bias0  = (float*)(ws + OFF_B0);
    float*  bias1  = (float*)(ws + OFF_B1);

    // ---- prologue: convert weights to bf16 row-major, fold biases (round-1 verbatim)
    for (int i = gtid; i < HID * 64; i += 65536) {
        int h = i >> 6, d = i & 63;
        wb_ih0[i] = f2bf(d < NA ? wih0[h * NA + d] : 0.f);
    }
    for (int i = gtid; i < HID * HID; i += 65536) wb_hh0[i] = f2bf(whh0[i]);
    for (int i = gtid; i < HID * HID; i += 65536) wb_ih1[i] = f2bf(wih1[i]);
    for (int i = gtid; i < HID * HID; i += 65536) wb_hh1[i] = f2bf(whh1[i]);
    for (int i = gtid; i < HID; i += 65536) {
        bias0[i] = bih0[i] + bhh0[i];
        bias1[i] = bih1[i] + bhh1[i];
    }
    grid.sync();

    // ---- role decode (round-1 verbatim)
    const int wg   = blockIdx.x;
    const int isG2 = (wg >= 128);
    const int w    = isG2 ? wg - 128 : wg;
    const int m0   = (w >> 4) << 6;           // batch-row tile base
    const int n0   = (w & 15) << 6;           // hidden-col tile base
    const int wave = tid >> 6, lane = tid & 63;
    const int wr = wave >> 1, wc = wave & 1;  // 2x2 waves over 64x64 tile
    const int g = lane >> 4, ln = lane & 15;

    // double-buffered LDS tiles (64 x 64, pitch 72)
    __shared__ ushort sAbuf[2][64 * LDSP];
    __shared__ ushort sBbuf[2][64 * LDSP];

    const int rowA = (wr << 5) + ln;
    const int rowB = (wc << 5) + ln;

    // per-thread staging geometry (round-1 stage_tile verbatim)
    const int sr = tid >> 3;            // 0..31
    const int sc = (tid & 7) << 3;      // 0,8,...,56

    #pragma unroll 1
    for (int it = 0; it <= TT; ++it) {
        const bool active = isG2 ? (it >= 1) : (it < TT);
        if (active) {
            f32x4 zero = {0.f, 0.f, 0.f, 0.f};
            f32x4 acc[2][2];
            acc[0][0] = zero; acc[0][1] = zero; acc[1][0] = zero; acc[1][1] = zero;

            const ushort* h1r = H1[it & 1];
            const ushort* h2r = H2[it & 1];

            u64x2 rA0, rA1, rB0, rB1;

            // issue global loads for chunk c into regs (sources per round-1 chunk map)
            auto issue = [&](int c) {
                const ushort *sa, *sb; int k0;
                if (!isG2)      { sa = h1r; sb = wb_hh0; k0 = (c - 1) << 6; }
                else if (c < 16){ sa = h1r; sb = wb_ih1; k0 = c << 6; }
                else            { sa = h2r; sb = wb_hh1; k0 = (c - 16) << 6; }
                const ushort* pa = sa + (size_t)(m0 + sr) * HID + k0 + sc;
                const ushort* pb = sb + (size_t)(n0 + sr) * HID + k0 + sc;
                rA0 = *(const u64x2*)pa;  rA1 = *(const u64x2*)(pa + (size_t)32 * HID);
                rB0 = *(const u64x2*)pb;  rB1 = *(const u64x2*)(pb + (size_t)32 * HID);
            };
            // commit staged regs to LDS buffer p
            auto commit = [&](int p) {
                *(u64x2*)(sAbuf[p] + sr * LDSP + sc)        = rA0;
                *(u64x2*)(sAbuf[p] + (sr + 32) * LDSP + sc) = rA1;
                *(u64x2*)(sBbuf[p] + sr * LDSP + sc)        = rB0;
                *(u64x2*)(sBbuf[p] + (sr + 32) * LDSP + sc) = rB1;
            };
            // MFMA on buffer p (round-1 inner loop verbatim)
            auto domfma = [&](int p) {
                const ushort* A = sAbuf[p];
                const ushort* B = sBbuf[p];
                #pragma unroll
                for (int kk = 0; kk < 64; kk += 32) {
                    v8s a0 = ld_frag(&A[rowA * LDSP + kk + (g << 2)]);
                    v8s a1 = ld_frag(&A[(rowA + 16) * LDSP + kk + (g << 2)]);
                    v8s b0 = ld_frag(&B[rowB * LDSP + kk + (g << 2)]);
                    v8s b1 = ld_frag(&B[(rowB + 16) * LDSP + kk + (g << 2)]);
                    acc[0][0] = __builtin_amdgcn_mfma_f32_16x16x32_bf16(a0, b0, acc[0][0], 0, 0, 0);
                    acc[0][1] = __builtin_amdgcn_mfma_f32_16x16x32_bf16(a0, b1, acc[0][1], 0, 0, 0);
                    acc[1][0] = __builtin_amdgcn_mfma_f32_16x16x32_bf16(a1, b0, acc[1][0], 0, 0, 0);
                    acc[1][1] = __builtin_amdgcn_mfma_f32_16x16x32_bf16(a1, b1, acc[1][1], 0, 0, 0);
                }
            };

            if (!isG2) {
                // ---- chunk 0: x tile (scalar stage, round-1 verbatim) + wb_ih0 B tile
                for (int idx = tid; idx < 64 * 64; idx += 256) {
                    int r_ = idx >> 6, cc = idx & 63;
                    float v = (cc < NA)
                        ? x[((size_t)(m0 + r_) * TT + it) * NA + cc] : 0.f;
                    sAbuf[0][r_ * LDSP + cc] = f2bf(v);
                }
                {
                    const ushort* pb = wb_ih0 + (size_t)(n0 + sr) * 64 + sc;
                    u64x2 b0v = *(const u64x2*)pb;
                    u64x2 b1v = *(const u64x2*)(pb + 32 * 64);
                    *(u64x2*)(sBbuf[0] + sr * LDSP + sc)        = b0v;
                    *(u64x2*)(sBbuf[0] + (sr + 32) * LDSP + sc) = b1v;
                }
                if (it > 0) issue(1);
                __syncthreads();
                domfma(0);
                if (it > 0) {
                    #pragma unroll 1
                    for (int c = 1; c <= 16; ++c) {
                        int p = c & 1;
                        commit(p);
                        __syncthreads();
                        if (c < 16) issue(c + 1);
                        domfma(p);
                    }
                }
            } else {
                const int nch = (it == 1) ? 16 : 32;
                issue(0);
                #pragma unroll 1
                for (int c = 0; c < nch; ++c) {
                    int p = c & 1;
                    commit(p);
                    __syncthreads();
                    if (c + 1 < nch) issue(c + 1);
                    domfma(p);
                }
            }
            __syncthreads();   // all waves done reading LDS before next-phase staging

            // ---- epilogue (round-1 verbatim): +bias, tanh, row-major bf16 store
            const float* bias = isG2 ? bias1 : bias0;
            ushort* dst = isG2 ? H2[(it + 1) & 1] : H1[(it + 1) & 1];
            #pragma unroll
            for (int fi = 0; fi < 2; ++fi)
            #pragma unroll
            for (int fj = 0; fj < 2; ++fj) {
                int col = n0 + (wc << 5) + (fj << 4) + ln;
                float bv = bias[col];
                #pragma unroll
                for (int j = 0; j < 4; ++j) {
                    int row = m0 + (wr << 5) + (fi << 4) + (g << 2) + j;
                    float v = tanh_fast(acc[fi][fj][j] + bv);
                    dst[(size_t)row * HID + col] = f2bf(v);
                    if (isG2 && it == TT) h2f[(size_t)row * HID + col] = v;
                }
            }
        }
        grid.sync();
    }
}

__device__ __forceinline__ float wsum(float v) {
    #pragma unroll
    for (int off = 32; off > 0; off >>= 1) v += __shfl_xor(v, off);
    return v;
}

__global__ __launch_bounds__(256) void fc_rebalance_kernel(
    const char* __restrict__ ws, const float* __restrict__ fc_w,
    const float* __restrict__ fc_b, float* __restrict__ out)
{
    const float* h2f = (const float*)(ws + OFF_H2F);
    const int wave = threadIdx.x >> 6, lane = threadIdx.x & 63;
    const int b = (blockIdx.x << 2) + wave;   // one wave per sample
    const float* hrow = h2f + (size_t)b * HID;

    float acc = 0.f;
    if (lane < NA) {
        const float* wrow = fc_w + (size_t)lane * HID;
        for (int k = 0; k < HID; k += 4) {
            float4 hv = *(const float4*)(hrow + k);
            float4 wv = *(const float4*)(wrow + k);
            acc += hv.x * wv.x + hv.y * wv.y + hv.z * wv.z + hv.w * wv.w;
        }
        acc += fc_b[lane];
    }
    float m = (lane < NA) ? acc : -3.402823466e+38f;
    #pragma unroll
    for (int off = 32; off > 0; off >>= 1) m = fmaxf(m, __shfl_xor(m, off));
    float e = (lane < NA) ? __expf(acc - m) : 0.f;
    float s = wsum(e);
    float p = e / s;

    float oldv = p;
    float wcv  = fminf(fmaxf(p, 0.f), 0.3f);
    #pragma unroll 1
    for (int i = 0; i < 16; ++i) {
        float leftover = wsum(oldv - wcv);
        float nom = (wcv != 0.3f) ? wcv : 0.f;
        float S = wsum(nom);
        float wc2 = wcv + leftover * nom / S;
        int cont = __any(wc2 > 0.3f);
        oldv = wc2;
        wcv = cont ? fminf(fmaxf(wc2, 0.f), 0.3f) : wc2;
    }
    if (lane < NA) out[(size_t)b * NA + lane] = wcv;
}

extern "C" void kernel_launch(void* const* d_in, const int* in_sizes, int n_in,
                              void* d_out, int out_size, void* d_ws, size_t ws_size,
                              hipStream_t stream) {
    const float* x    = (const float*)d_in[0];
    const float* wih0 = (const float*)d_in[1];
    const float* whh0 = (const float*)d_in[2];
    const float* bih0 = (const float*)d_in[3];
    const float* bhh0 = (const float*)d_in[4];
    const float* wih1 = (const float*)d_in[5];
    const float* whh1 = (const float*)d_in[6];
    const float* bih1 = (const float*)d_in[7];
    const float* bhh1 = (const float*)d_in[8];
    const float* fcw  = (const float*)d_in[9];
    const float* fcb  = (const float*)d_in[10];
    char* ws   = (char*)d_ws;
    float* out = (float*)d_out;

    void* args[] = { (void*)&x, (void*)&wih0, (void*)&whh0, (void*)&bih0, (void*)&bhh0,
                     (void*)&wih1, (void*)&whh1, (void*)&bih1, (void*)&bhh1, (void*)&ws };
    hipLaunchCooperativeKernel((const void*)rnn_coop_kernel,
                               dim3(256), dim3(256), args, 0, stream);
    fc_rebalance_kernel<<<dim3(128), dim3(256), 0, stream>>>(ws, fcw, fcb, out);
}